// Round 7
// baseline (126.629 us; speedup 1.0000x reference)
//
#include <hip/hip_runtime.h>
#include <hip/hip_bf16.h>

// Problem constants (fixed by setup_inputs: num_views=8, bs=4096, c=2048).
#define NV    8
#define BSZ   4096
#define CCH   2048
#define NPAIR 28          // NV*(NV-1)/2
#define NACC  36          // NV*(NV+1)/2 (upper triangle incl. diagonal)
#define BLK   64          // ONE wave per block; one block per batch row
#define VSTR  ((size_t)BSZ * CCH)   // float stride between views

// index of (v,w), v<=w, in the packed upper-triangular enumeration
__device__ __forceinline__ constexpr int triIdx(int v, int w) {
    return v * NV - (v * (v - 1)) / 2 + (w - v);
}

// One wave per batch row: no LDS, no __syncthreads. Load ISSUE order of the
// 8 view-streams is rotated by blockIdx to decorrelate DRAM stream phases
// across blocks; x[view] semantics (and therefore the math) are unchanged.
__global__ __launch_bounds__(BLK) void interviews_kernel(
        const float* __restrict__ in, float* __restrict__ out) {
    const int b    = blockIdx.x;      // batch row, 0..BSZ-1
    const int lane = threadIdx.x;     // 0..63
    const int rot  = b & (NV - 1);    // per-block stream-phase rotation

    float acc[NACC];
#pragma unroll
    for (int i = 0; i < NACC; ++i) acc[i] = 0.0f;

    // view v, batch b, channel c lives at in[v*VSTR + b*CCH + c]
    const float* base = in + (size_t)b * CCH + (size_t)lane * 4;

    // 2048 channels / (64 lanes * 4 floats) = 8 iterations; unroll 2 keeps
    // 16 float4 (64 VGPR) of load data in flight.
#pragma unroll 2
    for (int j = 0; j < CCH / (BLK * 4); ++j) {
        float4 x[NV];
#pragma unroll
        for (int u = 0; u < NV; ++u) {
            const int v = (u + rot) & (NV - 1);   // rotated issue order
            const float* p = base + (size_t)v * VSTR + (size_t)j * BLK * 4;
            x[v] = *reinterpret_cast<const float4*>(p);
        }
        int idx = 0;
#pragma unroll
        for (int v = 0; v < NV; ++v) {
#pragma unroll
            for (int w = v; w < NV; ++w) {
                acc[idx] += x[v].x * x[w].x + x[v].y * x[w].y
                          + x[v].z * x[w].z + x[v].w * x[w].w;
                ++idx;
            }
        }
    }

    // full-wave butterfly reduction; all lanes end with the complete sums
#pragma unroll
    for (int i = 0; i < NACC; ++i) {
        float v = acc[i];
#pragma unroll
        for (int off = 1; off < 64; off <<= 1)
            v += __shfl_xor(v, off, 64);
        acc[i] = v;
    }

    if (lane == 0) {
        float rn[NV];
#pragma unroll
        for (int v = 0; v < NV; ++v)
            rn[v] = 1.0f / sqrtf(acc[triIdx(v, v)]);

        float s[NPAIR];
        float mean = 0.0f;
        int k = 0;
#pragma unroll
        for (int v = 0; v < NV; ++v) {
#pragma unroll
            for (int w = v + 1; w < NV; ++w) {
                s[k] = acc[triIdx(v, w)] * rn[v] * rn[w];
                mean += s[k];
                ++k;
            }
        }
        mean *= (1.0f / NPAIR);

        float var = 0.0f;
#pragma unroll
        for (int i = 0; i < NPAIR; ++i) {
            float d = s[i] - mean;
            var += d * d;
        }
        var *= (1.0f / (NPAIR - 1));   // ddof=1

        out[b] = -var;
    }
}

extern "C" void kernel_launch(void* const* d_in, const int* in_sizes, int n_in,
                              void* d_out, int out_size, void* d_ws, size_t ws_size,
                              hipStream_t stream) {
    const float* in = (const float*)d_in[0];
    float* out = (float*)d_out;
    // out_size == BSZ (4096); one 64-thread block (one wave) per batch row
    interviews_kernel<<<dim3(out_size), dim3(BLK), 0, stream>>>(in, out);
}

// Round 8
// 46.739 us; speedup vs baseline: 2.7093x; 2.7093x over previous
//
#include <hip/hip_runtime.h>
#include <hip/hip_bf16.h>

// Problem constants (fixed by setup_inputs: num_views=8, bs=4096, c=2048).
#define NV    8
#define BSZ   4096
#define CCH   2048
#define NPAIR 28          // NV*(NV-1)/2
#define NACC  36          // NV*(NV+1)/2 (upper triangle incl. diagonal)
#define BLK   64          // ONE wave per block; one block per batch row
#define VSTR  ((size_t)BSZ * CCH)   // float stride between views

// index of (v,w), v<=w, in the packed upper-triangular enumeration
__device__ __forceinline__ constexpr int triIdx(int v, int w) {
    return v * NV - (v * (v - 1)) / 2 + (w - v);
}

// One wave per batch row: no LDS, no __syncthreads, 216-shuffle reduce
// amortized over the full 64 KB batch stream.
// NOTE (R7 lesson): all x[]/acc[] indices MUST be compile-time constants —
// any runtime index demotes the array to scratch (84 VGPR, +171 MB spill
// traffic, 2.7x slowdown measured).
__global__ __launch_bounds__(BLK) void interviews_kernel(
        const float* __restrict__ in, float* __restrict__ out) {
    const int b    = blockIdx.x;      // batch row, 0..BSZ-1
    const int lane = threadIdx.x;     // 0..63

    float acc[NACC];
#pragma unroll
    for (int i = 0; i < NACC; ++i) acc[i] = 0.0f;

    // view v, batch b, channel c lives at in[v*VSTR + b*CCH + c]
    const float* base = in + (size_t)b * CCH + (size_t)lane * 4;

    // 2048 channels / (64 lanes * 4 floats) = 8 iterations; unroll 2 keeps
    // 16 float4 (64 VGPR) of load data in flight.
#pragma unroll 2
    for (int j = 0; j < CCH / (BLK * 4); ++j) {
        float4 x[NV];
#pragma unroll
        for (int v = 0; v < NV; ++v) {
            const float* p = base + (size_t)v * VSTR + (size_t)j * BLK * 4;
            x[v] = *reinterpret_cast<const float4*>(p);
        }
        int idx = 0;
#pragma unroll
        for (int v = 0; v < NV; ++v) {
#pragma unroll
            for (int w = v; w < NV; ++w) {
                acc[idx] += x[v].x * x[w].x + x[v].y * x[w].y
                          + x[v].z * x[w].z + x[v].w * x[w].w;
                ++idx;
            }
        }
    }

    // full-wave butterfly reduction; all lanes end with the complete sums
#pragma unroll
    for (int i = 0; i < NACC; ++i) {
        float v = acc[i];
#pragma unroll
        for (int off = 1; off < 64; off <<= 1)
            v += __shfl_xor(v, off, 64);
        acc[i] = v;
    }

    if (lane == 0) {
        float rn[NV];
#pragma unroll
        for (int v = 0; v < NV; ++v)
            rn[v] = 1.0f / sqrtf(acc[triIdx(v, v)]);

        float s[NPAIR];
        float mean = 0.0f;
        int k = 0;
#pragma unroll
        for (int v = 0; v < NV; ++v) {
#pragma unroll
            for (int w = v + 1; w < NV; ++w) {
                s[k] = acc[triIdx(v, w)] * rn[v] * rn[w];
                mean += s[k];
                ++k;
            }
        }
        mean *= (1.0f / NPAIR);

        float var = 0.0f;
#pragma unroll
        for (int i = 0; i < NPAIR; ++i) {
            float d = s[i] - mean;
            var += d * d;
        }
        var *= (1.0f / (NPAIR - 1));   // ddof=1

        out[b] = -var;
    }
}

extern "C" void kernel_launch(void* const* d_in, const int* in_sizes, int n_in,
                              void* d_out, int out_size, void* d_ws, size_t ws_size,
                              hipStream_t stream) {
    const float* in = (const float*)d_in[0];
    float* out = (float*)d_out;
    // out_size == BSZ (4096); one 64-thread block (one wave) per batch row
    interviews_kernel<<<dim3(out_size), dim3(BLK), 0, stream>>>(in, out);
}